// Round 1
// baseline (895.832 us; speedup 1.0000x reference)
//
#include <hip/hip_runtime.h>
#include <math.h>

#define N_NODES 50000
#define N_EDGES 800000
#define D 128
#define E_DIM 16
#define DEPTH 3

// ---------------- CSR build (by dst) ----------------

__global__ void k_hist(const int* __restrict__ dst, int* __restrict__ deg) {
    int e = blockIdx.x * blockDim.x + threadIdx.x;
    if (e < N_EDGES) atomicAdd(&deg[dst[e]], 1);
}

// block-level inclusive scan: each block handles 1024 elements (4/thread)
__global__ void k_scan1(const int* __restrict__ deg, int* __restrict__ out1 /* = off+1 */,
                        int* __restrict__ bsum) {
    __shared__ int s[256];
    int t = threadIdx.x;
    int base = blockIdx.x * 1024;
    int v[4]; int sum = 0;
#pragma unroll
    for (int j = 0; j < 4; j++) {
        int idx = base + t * 4 + j;
        int x = (idx < N_NODES) ? deg[idx] : 0;
        v[j] = x; sum += x;
    }
    s[t] = sum;
    __syncthreads();
    for (int d2 = 1; d2 < 256; d2 <<= 1) {
        int val = (t >= d2) ? s[t - d2] : 0;
        __syncthreads();
        s[t] += val;
        __syncthreads();
    }
    int run = (t > 0) ? s[t - 1] : 0;
#pragma unroll
    for (int j = 0; j < 4; j++) {
        int idx = base + t * 4 + j;
        run += v[j];
        if (idx < N_NODES) out1[idx] = run;
    }
    if (t == 255) bsum[blockIdx.x] = s[255];
}

// tiny exclusive scan of the 49 block sums (single thread; 49 adds)
__global__ void k_scan2(int* bsum, int nb) {
    if (threadIdx.x == 0 && blockIdx.x == 0) {
        int run = 0;
        for (int i = 0; i < nb; i++) { int v = bsum[i]; bsum[i] = run; run += v; }
    }
}

// fix up offsets with block sums; also produce head[] (scatter cursors)
__global__ void k_scanadd(int* __restrict__ off, const int* __restrict__ bsum,
                          int* __restrict__ head) {
    int i = blockIdx.x * blockDim.x + threadIdx.x;
    if (i == 0) { off[0] = 0; head[0] = 0; }
    if (i < N_NODES) {
        int v = off[i + 1] + bsum[i / 1024];
        off[i + 1] = v;
        if (i + 1 < N_NODES) head[i + 1] = v;
    }
}

__global__ void k_scatter(const int* __restrict__ src, const int* __restrict__ dst,
                          int* __restrict__ head, int2* __restrict__ sorted) {
    int e = blockIdx.x * blockDim.x + threadIdx.x;
    if (e < N_EDGES) {
        int d = dst[e];
        int pos = atomicAdd(&head[d], 1);
        sorted[pos] = make_int2(src[e], e);
    }
}

// ---------------- per-layer: aggregation (one wave per node) ----------------
// h0[i] = (1+eps)*x[i] + sum_{e: dst==i} relu(x[src_e] + edge_attr[e]@We + be)

__global__ __launch_bounds__(256) void k_agg(
    const float* __restrict__ x, const float* __restrict__ edge_attr,
    const int2* __restrict__ sorted, const int* __restrict__ off,
    const float* __restrict__ We_l, const float* __restrict__ be_l,
    const float* __restrict__ eps_ptr, float* __restrict__ h0) {
    int wave = (blockIdx.x * blockDim.x + threadIdx.x) >> 6;
    int lane = threadIdx.x & 63;
    if (wave >= N_NODES) return;

    // We columns for this lane's two features, in registers
    float wc0[E_DIM], wc1[E_DIM];
#pragma unroll
    for (int k = 0; k < E_DIM; k++) {
        wc0[k] = We_l[k * D + lane];
        wc1[k] = We_l[k * D + 64 + lane];
    }
    float be0 = be_l[lane], be1 = be_l[64 + lane];

    float acc0 = 0.f, acc1 = 0.f;
    int t0 = off[wave], t1 = off[wave + 1];
    for (int t = t0; t < t1; ++t) {
        int2 se = sorted[t];  // (src, edge_id), wave-uniform
        const float4* ea = (const float4*)(edge_attr + (size_t)se.y * E_DIM);
        float4 a = ea[0], b = ea[1], c = ea[2], d4 = ea[3];
        float ev[16] = {a.x, a.y, a.z, a.w, b.x, b.y, b.z, b.w,
                        c.x, c.y, c.z, c.w, d4.x, d4.y, d4.z, d4.w};
        float e0 = be0, e1 = be1;
#pragma unroll
        for (int k = 0; k < 16; k++) {
            e0 = fmaf(ev[k], wc0[k], e0);
            e1 = fmaf(ev[k], wc1[k], e1);
        }
        const float* xs = x + (size_t)se.x * D;
        float m0 = xs[lane] + e0;
        float m1 = xs[64 + lane] + e1;
        acc0 += fmaxf(m0, 0.f);
        acc1 += fmaxf(m1, 0.f);
    }
    float epsv = 1.0f + eps_ptr[0];
    size_t o = (size_t)wave * D;
    h0[o + lane] = epsv * x[o + lane] + acc0;
    h0[o + 64 + lane] = epsv * x[o + 64 + lane] + acc1;
}

// ---------------- per-layer: fused node MLP ----------------
// out = gelu_exact(h0 @ W1 + b1) @ W2 + b2

__device__ __forceinline__ float gelu_exact(float v) {
    return 0.5f * v * (1.0f + erff(v * 0.70710678118654752f));
}

__global__ __launch_bounds__(256) void k_mlp(
    const float* __restrict__ h0, const float* __restrict__ W1,
    const float* __restrict__ b1, const float* __restrict__ W2,
    const float* __restrict__ b2, float* __restrict__ out) {
    __shared__ float sH[64][D];  // 32 KB
    __shared__ float sG[64][D];  // 32 KB  -> total 64 KB, 2 blocks/CU
    int n0 = blockIdx.x * 64;
    int t = threadIdx.x;

    // stage h tile (coalesced float4)
    for (int i = t; i < 64 * D / 4; i += 256) {
        int idx = i * 4;
        int n = idx / D, k = idx % D;
        float4 v = (n0 + n < N_NODES) ? *(const float4*)&h0[(size_t)(n0 + n) * D + k]
                                      : make_float4(0.f, 0.f, 0.f, 0.f);
        *(float4*)&sH[n][k] = v;
    }
    __syncthreads();

    int tx = t & 31;   // feature group: feats 4*tx .. 4*tx+3
    int ty = t >> 5;   // node group: nodes 8*ty .. 8*ty+7
    float acc[8][4];

    // ---- phase 1: g = gelu(h @ W1 + b1) ----
    {
        float4 bb = *(const float4*)&b1[4 * tx];
#pragma unroll
        for (int i = 0; i < 8; i++) {
            acc[i][0] = bb.x; acc[i][1] = bb.y; acc[i][2] = bb.z; acc[i][3] = bb.w;
        }
#pragma unroll 8
        for (int k = 0; k < D; k++) {
            float4 w = *(const float4*)&W1[k * D + 4 * tx];
#pragma unroll
            for (int i = 0; i < 8; i++) {
                float hv = sH[8 * ty + i][k];
                acc[i][0] = fmaf(hv, w.x, acc[i][0]);
                acc[i][1] = fmaf(hv, w.y, acc[i][1]);
                acc[i][2] = fmaf(hv, w.z, acc[i][2]);
                acc[i][3] = fmaf(hv, w.w, acc[i][3]);
            }
        }
#pragma unroll
        for (int i = 0; i < 8; i++) {
            float4 g;
            g.x = gelu_exact(acc[i][0]);
            g.y = gelu_exact(acc[i][1]);
            g.z = gelu_exact(acc[i][2]);
            g.w = gelu_exact(acc[i][3]);
            *(float4*)&sG[8 * ty + i][4 * tx] = g;
        }
    }
    __syncthreads();

    // ---- phase 2: out = g @ W2 + b2 ----
    {
        float4 bb = *(const float4*)&b2[4 * tx];
#pragma unroll
        for (int i = 0; i < 8; i++) {
            acc[i][0] = bb.x; acc[i][1] = bb.y; acc[i][2] = bb.z; acc[i][3] = bb.w;
        }
#pragma unroll 8
        for (int k = 0; k < D; k++) {
            float4 w = *(const float4*)&W2[k * D + 4 * tx];
#pragma unroll
            for (int i = 0; i < 8; i++) {
                float gv = sG[8 * ty + i][k];
                acc[i][0] = fmaf(gv, w.x, acc[i][0]);
                acc[i][1] = fmaf(gv, w.y, acc[i][1]);
                acc[i][2] = fmaf(gv, w.z, acc[i][2]);
                acc[i][3] = fmaf(gv, w.w, acc[i][3]);
            }
        }
#pragma unroll
        for (int i = 0; i < 8; i++) {
            int n = n0 + 8 * ty + i;
            if (n < N_NODES) {
                float4 o4 = make_float4(acc[i][0], acc[i][1], acc[i][2], acc[i][3]);
                *(float4*)&out[(size_t)n * D + 4 * tx] = o4;
            }
        }
    }
}

// ---------------- launch ----------------

static inline size_t align_up(size_t v, size_t a) { return (v + a - 1) & ~(a - 1); }

extern "C" void kernel_launch(void* const* d_in, const int* in_sizes, int n_in,
                              void* d_out, int out_size, void* d_ws, size_t ws_size,
                              hipStream_t stream) {
    const float* x         = (const float*)d_in[0];
    const float* edge_attr = (const float*)d_in[1];
    const float* W1        = (const float*)d_in[2];
    const float* b1        = (const float*)d_in[3];
    const float* W2        = (const float*)d_in[4];
    const float* b2        = (const float*)d_in[5];
    const float* We        = (const float*)d_in[6];
    const float* be        = (const float*)d_in[7];
    const float* eps       = (const float*)d_in[8];
    const int*   src       = (const int*)d_in[9];            // edge_idx[0]
    const int*   dst       = ((const int*)d_in[9]) + N_EDGES; // edge_idx[1]

    char* w = (char*)d_ws;
    int*  off    = (int*)w;  w += align_up((N_NODES + 1) * sizeof(int), 16);
    int*  deg    = (int*)w;  w += align_up(N_NODES * sizeof(int), 16);
    int*  head   = (int*)w;  w += align_up(N_NODES * sizeof(int), 16);
    int*  bsum   = (int*)w;  w += 256;
    int2* sorted = (int2*)w; w += (size_t)N_EDGES * sizeof(int2);
    float* bufA  = (float*)w; w += (size_t)N_NODES * D * sizeof(float);
    float* bufC  = (float*)w; w += (size_t)N_NODES * D * sizeof(float);

    // ---- CSR build (once per launch; reused across the 3 layers) ----
    hipMemsetAsync(deg, 0, N_NODES * sizeof(int), stream);
    k_hist<<<(N_EDGES + 255) / 256, 256, 0, stream>>>(dst, deg);
    int nb1 = (N_NODES + 1023) / 1024;  // 49
    k_scan1<<<nb1, 256, 0, stream>>>(deg, off + 1, bsum);
    k_scan2<<<1, 64, 0, stream>>>(bsum, nb1);
    k_scanadd<<<(N_NODES + 255) / 256, 256, 0, stream>>>(off, bsum, head);
    k_scatter<<<(N_EDGES + 255) / 256, 256, 0, stream>>>(src, dst, head, sorted);

    // ---- 3 layers ----
    const float* xin = x;
    for (int l = 0; l < DEPTH; l++) {
        k_agg<<<(N_NODES + 3) / 4, 256, 0, stream>>>(
            xin, edge_attr, sorted, off,
            We + (size_t)l * E_DIM * D, be + (size_t)l * D, eps + l, bufC);
        float* out_l = (l == DEPTH - 1) ? (float*)d_out : bufA;
        k_mlp<<<(N_NODES + 63) / 64, 256, 0, stream>>>(
            bufC, W1 + (size_t)l * D * D, b1 + (size_t)l * D,
            W2 + (size_t)l * D * D, b2 + (size_t)l * D, out_l);
        xin = bufA;
    }
}

// Round 2
// 681.970 us; speedup vs baseline: 1.3136x; 1.3136x over previous
//
#include <hip/hip_runtime.h>
#include <math.h>

#define N_NODES 50000
#define N_EDGES 800000
#define D 128
#define E_DIM 16
#define DEPTH 3

// ---------------- CSR build (by dst) ----------------

__global__ void k_hist(const int* __restrict__ dst, int* __restrict__ deg) {
    int e = blockIdx.x * blockDim.x + threadIdx.x;
    if (e < N_EDGES) atomicAdd(&deg[dst[e]], 1);
}

// block-level inclusive scan: each block handles 1024 elements (4/thread)
__global__ void k_scan1(const int* __restrict__ deg, int* __restrict__ out1 /* = off+1 */,
                        int* __restrict__ bsum) {
    __shared__ int s[256];
    int t = threadIdx.x;
    int base = blockIdx.x * 1024;
    int v[4]; int sum = 0;
#pragma unroll
    for (int j = 0; j < 4; j++) {
        int idx = base + t * 4 + j;
        int x = (idx < N_NODES) ? deg[idx] : 0;
        v[j] = x; sum += x;
    }
    s[t] = sum;
    __syncthreads();
    for (int d2 = 1; d2 < 256; d2 <<= 1) {
        int val = (t >= d2) ? s[t - d2] : 0;
        __syncthreads();
        s[t] += val;
        __syncthreads();
    }
    int run = (t > 0) ? s[t - 1] : 0;
#pragma unroll
    for (int j = 0; j < 4; j++) {
        int idx = base + t * 4 + j;
        run += v[j];
        if (idx < N_NODES) out1[idx] = run;
    }
    if (t == 255) bsum[blockIdx.x] = s[255];
}

// tiny exclusive scan of the 49 block sums (single thread; 49 adds)
__global__ void k_scan2(int* bsum, int nb) {
    if (threadIdx.x == 0 && blockIdx.x == 0) {
        int run = 0;
        for (int i = 0; i < nb; i++) { int v = bsum[i]; bsum[i] = run; run += v; }
    }
}

// fix up offsets with block sums; also produce head[] (scatter cursors)
__global__ void k_scanadd(int* __restrict__ off, const int* __restrict__ bsum,
                          int* __restrict__ head) {
    int i = blockIdx.x * blockDim.x + threadIdx.x;
    if (i == 0) { off[0] = 0; head[0] = 0; }
    if (i < N_NODES) {
        int v = off[i + 1] + bsum[i / 1024];
        off[i + 1] = v;
        if (i + 1 < N_NODES) head[i + 1] = v;
    }
}

__global__ void k_scatter(const int* __restrict__ src, const int* __restrict__ dst,
                          int* __restrict__ head, int2* __restrict__ sorted) {
    int e = blockIdx.x * blockDim.x + threadIdx.x;
    if (e < N_EDGES) {
        int d = dst[e];
        int pos = atomicAdd(&head[d], 1);
        sorted[pos] = make_int2(src[e], e);
    }
}

// ---------------- per-layer: aggregation (one wave per node) ----------------
// h0[i] = (1+eps)*x[i] + sum_{e: dst==i} relu(x[src_e] + edge_attr[e]@We + be)
//
// Latency fix vs r1: batch 4 edges/iter so the 4 edge-attr reads + 8 x-gathers
// are all in flight together; readfirstlane the wave-uniform indices so the
// edge-attr rows go through the scalar (s_load) path into SGPRs.

__global__ __launch_bounds__(256) void k_agg(
    const float* __restrict__ x, const float* __restrict__ edge_attr,
    const int2* __restrict__ sorted, const int* __restrict__ off,
    const float* __restrict__ We_l, const float* __restrict__ be_l,
    const float* __restrict__ eps_ptr, float* __restrict__ h0) {
    int wave = (blockIdx.x * blockDim.x + threadIdx.x) >> 6;
    int lane = threadIdx.x & 63;
    if (wave >= N_NODES) return;

    // We columns for this lane's two features, in registers
    float wc0[E_DIM], wc1[E_DIM];
#pragma unroll
    for (int k = 0; k < E_DIM; k++) {
        wc0[k] = We_l[k * D + lane];
        wc1[k] = We_l[k * D + 64 + lane];
    }
    float be0 = be_l[lane], be1 = be_l[64 + lane];

    float acc0 = 0.f, acc1 = 0.f;
    int t0 = __builtin_amdgcn_readfirstlane(off[wave]);
    int t1 = __builtin_amdgcn_readfirstlane(off[wave + 1]);
    int t = t0;

    // main loop: 4 edges in flight
    for (; t + 4 <= t1; t += 4) {
        int2 a = sorted[t], b = sorted[t + 1], c = sorted[t + 2], d4 = sorted[t + 3];
        int s0 = __builtin_amdgcn_readfirstlane(a.x);
        int e0 = __builtin_amdgcn_readfirstlane(a.y);
        int s1 = __builtin_amdgcn_readfirstlane(b.x);
        int e1 = __builtin_amdgcn_readfirstlane(b.y);
        int s2 = __builtin_amdgcn_readfirstlane(c.x);
        int e2 = __builtin_amdgcn_readfirstlane(c.y);
        int s3 = __builtin_amdgcn_readfirstlane(d4.x);
        int e3 = __builtin_amdgcn_readfirstlane(d4.y);

        const float* ea0 = edge_attr + (size_t)e0 * E_DIM;
        const float* ea1 = edge_attr + (size_t)e1 * E_DIM;
        const float* ea2 = edge_attr + (size_t)e2 * E_DIM;
        const float* ea3 = edge_attr + (size_t)e3 * E_DIM;
        float ev0[16], ev1[16], ev2[16], ev3[16];
#pragma unroll
        for (int k = 0; k < 16; k++) {
            ev0[k] = ea0[k]; ev1[k] = ea1[k]; ev2[k] = ea2[k]; ev3[k] = ea3[k];
        }

        const float* xs0 = x + (size_t)s0 * D;
        const float* xs1 = x + (size_t)s1 * D;
        const float* xs2 = x + (size_t)s2 * D;
        const float* xs3 = x + (size_t)s3 * D;
        float x00 = xs0[lane], x01 = xs0[64 + lane];
        float x10 = xs1[lane], x11 = xs1[64 + lane];
        float x20 = xs2[lane], x21 = xs2[64 + lane];
        float x30 = xs3[lane], x31 = xs3[64 + lane];

        float p00 = be0, p01 = be1, p10 = be0, p11 = be1;
        float p20 = be0, p21 = be1, p30 = be0, p31 = be1;
#pragma unroll
        for (int k = 0; k < 16; k++) {
            p00 = fmaf(ev0[k], wc0[k], p00); p01 = fmaf(ev0[k], wc1[k], p01);
            p10 = fmaf(ev1[k], wc0[k], p10); p11 = fmaf(ev1[k], wc1[k], p11);
            p20 = fmaf(ev2[k], wc0[k], p20); p21 = fmaf(ev2[k], wc1[k], p21);
            p30 = fmaf(ev3[k], wc0[k], p30); p31 = fmaf(ev3[k], wc1[k], p31);
        }
        acc0 += fmaxf(x00 + p00, 0.f); acc1 += fmaxf(x01 + p01, 0.f);
        acc0 += fmaxf(x10 + p10, 0.f); acc1 += fmaxf(x11 + p11, 0.f);
        acc0 += fmaxf(x20 + p20, 0.f); acc1 += fmaxf(x21 + p21, 0.f);
        acc0 += fmaxf(x30 + p30, 0.f); acc1 += fmaxf(x31 + p31, 0.f);
    }

    // remainder (<=3 edges)
    for (; t < t1; ++t) {
        int2 se = sorted[t];
        int s0 = __builtin_amdgcn_readfirstlane(se.x);
        int e0 = __builtin_amdgcn_readfirstlane(se.y);
        const float* ea = edge_attr + (size_t)e0 * E_DIM;
        const float* xs = x + (size_t)s0 * D;
        float xv0 = xs[lane], xv1 = xs[64 + lane];
        float p0 = be0, p1 = be1;
#pragma unroll
        for (int k = 0; k < 16; k++) {
            float v = ea[k];
            p0 = fmaf(v, wc0[k], p0);
            p1 = fmaf(v, wc1[k], p1);
        }
        acc0 += fmaxf(xv0 + p0, 0.f);
        acc1 += fmaxf(xv1 + p1, 0.f);
    }

    float epsv = 1.0f + eps_ptr[0];
    size_t o = (size_t)wave * D;
    h0[o + lane] = epsv * x[o + lane] + acc0;
    h0[o + 64 + lane] = epsv * x[o + 64 + lane] + acc1;
}

// ---------------- per-layer: fused node MLP ----------------
// out = gelu_exact(h0 @ W1 + b1) @ W2 + b2

__device__ __forceinline__ float gelu_exact(float v) {
    return 0.5f * v * (1.0f + erff(v * 0.70710678118654752f));
}

__global__ __launch_bounds__(256) void k_mlp(
    const float* __restrict__ h0, const float* __restrict__ W1,
    const float* __restrict__ b1, const float* __restrict__ W2,
    const float* __restrict__ b2, float* __restrict__ out) {
    __shared__ float sH[64][D];  // 32 KB
    __shared__ float sG[64][D];  // 32 KB  -> total 64 KB, 2 blocks/CU
    int n0 = blockIdx.x * 64;
    int t = threadIdx.x;

    // stage h tile (coalesced float4)
    for (int i = t; i < 64 * D / 4; i += 256) {
        int idx = i * 4;
        int n = idx / D, k = idx % D;
        float4 v = (n0 + n < N_NODES) ? *(const float4*)&h0[(size_t)(n0 + n) * D + k]
                                      : make_float4(0.f, 0.f, 0.f, 0.f);
        *(float4*)&sH[n][k] = v;
    }
    __syncthreads();

    int tx = t & 31;   // feature group: feats 4*tx .. 4*tx+3
    int ty = t >> 5;   // node group: nodes 8*ty .. 8*ty+7
    float acc[8][4];

    // ---- phase 1: g = gelu(h @ W1 + b1) ----
    {
        float4 bb = *(const float4*)&b1[4 * tx];
#pragma unroll
        for (int i = 0; i < 8; i++) {
            acc[i][0] = bb.x; acc[i][1] = bb.y; acc[i][2] = bb.z; acc[i][3] = bb.w;
        }
        for (int k = 0; k < D; k += 4) {
            float4 w0 = *(const float4*)&W1[(k + 0) * D + 4 * tx];
            float4 w1 = *(const float4*)&W1[(k + 1) * D + 4 * tx];
            float4 w2 = *(const float4*)&W1[(k + 2) * D + 4 * tx];
            float4 w3 = *(const float4*)&W1[(k + 3) * D + 4 * tx];
#pragma unroll
            for (int i = 0; i < 8; i++) {
                float4 hv = *(const float4*)&sH[8 * ty + i][k];
                acc[i][0] = fmaf(hv.x, w0.x, acc[i][0]);
                acc[i][1] = fmaf(hv.x, w0.y, acc[i][1]);
                acc[i][2] = fmaf(hv.x, w0.z, acc[i][2]);
                acc[i][3] = fmaf(hv.x, w0.w, acc[i][3]);
                acc[i][0] = fmaf(hv.y, w1.x, acc[i][0]);
                acc[i][1] = fmaf(hv.y, w1.y, acc[i][1]);
                acc[i][2] = fmaf(hv.y, w1.z, acc[i][2]);
                acc[i][3] = fmaf(hv.y, w1.w, acc[i][3]);
                acc[i][0] = fmaf(hv.z, w2.x, acc[i][0]);
                acc[i][1] = fmaf(hv.z, w2.y, acc[i][1]);
                acc[i][2] = fmaf(hv.z, w2.z, acc[i][2]);
                acc[i][3] = fmaf(hv.z, w2.w, acc[i][3]);
                acc[i][0] = fmaf(hv.w, w3.x, acc[i][0]);
                acc[i][1] = fmaf(hv.w, w3.y, acc[i][1]);
                acc[i][2] = fmaf(hv.w, w3.z, acc[i][2]);
                acc[i][3] = fmaf(hv.w, w3.w, acc[i][3]);
            }
        }
#pragma unroll
        for (int i = 0; i < 8; i++) {
            float4 g;
            g.x = gelu_exact(acc[i][0]);
            g.y = gelu_exact(acc[i][1]);
            g.z = gelu_exact(acc[i][2]);
            g.w = gelu_exact(acc[i][3]);
            *(float4*)&sG[8 * ty + i][4 * tx] = g;
        }
    }
    __syncthreads();

    // ---- phase 2: out = g @ W2 + b2 ----
    {
        float4 bb = *(const float4*)&b2[4 * tx];
#pragma unroll
        for (int i = 0; i < 8; i++) {
            acc[i][0] = bb.x; acc[i][1] = bb.y; acc[i][2] = bb.z; acc[i][3] = bb.w;
        }
        for (int k = 0; k < D; k += 4) {
            float4 w0 = *(const float4*)&W2[(k + 0) * D + 4 * tx];
            float4 w1 = *(const float4*)&W2[(k + 1) * D + 4 * tx];
            float4 w2 = *(const float4*)&W2[(k + 2) * D + 4 * tx];
            float4 w3 = *(const float4*)&W2[(k + 3) * D + 4 * tx];
#pragma unroll
            for (int i = 0; i < 8; i++) {
                float4 gv = *(const float4*)&sG[8 * ty + i][k];
                acc[i][0] = fmaf(gv.x, w0.x, acc[i][0]);
                acc[i][1] = fmaf(gv.x, w0.y, acc[i][1]);
                acc[i][2] = fmaf(gv.x, w0.z, acc[i][2]);
                acc[i][3] = fmaf(gv.x, w0.w, acc[i][3]);
                acc[i][0] = fmaf(gv.y, w1.x, acc[i][0]);
                acc[i][1] = fmaf(gv.y, w1.y, acc[i][1]);
                acc[i][2] = fmaf(gv.y, w1.z, acc[i][2]);
                acc[i][3] = fmaf(gv.y, w1.w, acc[i][3]);
                acc[i][0] = fmaf(gv.z, w2.x, acc[i][0]);
                acc[i][1] = fmaf(gv.z, w2.y, acc[i][1]);
                acc[i][2] = fmaf(gv.z, w2.z, acc[i][2]);
                acc[i][3] = fmaf(gv.z, w2.w, acc[i][3]);
                acc[i][0] = fmaf(gv.w, w3.x, acc[i][0]);
                acc[i][1] = fmaf(gv.w, w3.y, acc[i][1]);
                acc[i][2] = fmaf(gv.w, w3.z, acc[i][2]);
                acc[i][3] = fmaf(gv.w, w3.w, acc[i][3]);
            }
        }
#pragma unroll
        for (int i = 0; i < 8; i++) {
            int n = n0 + 8 * ty + i;
            if (n < N_NODES) {
                float4 o4 = make_float4(acc[i][0], acc[i][1], acc[i][2], acc[i][3]);
                *(float4*)&out[(size_t)n * D + 4 * tx] = o4;
            }
        }
    }
}

// ---------------- launch ----------------

static inline size_t align_up(size_t v, size_t a) { return (v + a - 1) & ~(a - 1); }

extern "C" void kernel_launch(void* const* d_in, const int* in_sizes, int n_in,
                              void* d_out, int out_size, void* d_ws, size_t ws_size,
                              hipStream_t stream) {
    const float* x         = (const float*)d_in[0];
    const float* edge_attr = (const float*)d_in[1];
    const float* W1        = (const float*)d_in[2];
    const float* b1        = (const float*)d_in[3];
    const float* W2        = (const float*)d_in[4];
    const float* b2        = (const float*)d_in[5];
    const float* We        = (const float*)d_in[6];
    const float* be        = (const float*)d_in[7];
    const float* eps       = (const float*)d_in[8];
    const int*   src       = (const int*)d_in[9];             // edge_idx[0]
    const int*   dst       = ((const int*)d_in[9]) + N_EDGES; // edge_idx[1]

    char* w = (char*)d_ws;
    int*  off    = (int*)w;  w += align_up((N_NODES + 1) * sizeof(int), 16);
    int*  deg    = (int*)w;  w += align_up(N_NODES * sizeof(int), 16);
    int*  head   = (int*)w;  w += align_up(N_NODES * sizeof(int), 16);
    int*  bsum   = (int*)w;  w += 256;
    int2* sorted = (int2*)w; w += (size_t)N_EDGES * sizeof(int2);
    float* bufA  = (float*)w; w += (size_t)N_NODES * D * sizeof(float);
    float* bufC  = (float*)w; w += (size_t)N_NODES * D * sizeof(float);

    // ---- CSR build (once per launch; reused across the 3 layers) ----
    hipMemsetAsync(deg, 0, N_NODES * sizeof(int), stream);
    k_hist<<<(N_EDGES + 255) / 256, 256, 0, stream>>>(dst, deg);
    int nb1 = (N_NODES + 1023) / 1024;  // 49
    k_scan1<<<nb1, 256, 0, stream>>>(deg, off + 1, bsum);
    k_scan2<<<1, 64, 0, stream>>>(bsum, nb1);
    k_scanadd<<<(N_NODES + 255) / 256, 256, 0, stream>>>(off, bsum, head);
    k_scatter<<<(N_EDGES + 255) / 256, 256, 0, stream>>>(src, dst, head, sorted);

    // ---- 3 layers ----
    const float* xin = x;
    for (int l = 0; l < DEPTH; l++) {
        k_agg<<<(N_NODES + 3) / 4, 256, 0, stream>>>(
            xin, edge_attr, sorted, off,
            We + (size_t)l * E_DIM * D, be + (size_t)l * D, eps + l, bufC);
        float* out_l = (l == DEPTH - 1) ? (float*)d_out : bufA;
        k_mlp<<<(N_NODES + 63) / 64, 256, 0, stream>>>(
            bufC, W1 + (size_t)l * D * D, b1 + (size_t)l * D,
            W2 + (size_t)l * D * D, b2 + (size_t)l * D, out_l);
        xin = bufA;
    }
}

// Round 3
// 570.481 us; speedup vs baseline: 1.5703x; 1.1954x over previous
//
#include <hip/hip_runtime.h>
#include <math.h>

#define N_NODES 50000
#define N_EDGES 800000
#define D 128
#define E_DIM 16
#define DEPTH 3

typedef _Float16 half2_t __attribute__((ext_vector_type(2)));
typedef _Float16 half8_t __attribute__((ext_vector_type(8)));
typedef float floatx4 __attribute__((ext_vector_type(4)));

#if defined(__has_builtin)
#if __has_builtin(__builtin_amdgcn_fdot2)
#define FDOT2(a, b, c) __builtin_amdgcn_fdot2((a), (b), (c), false)
#endif
#endif
#ifndef FDOT2
static __device__ __forceinline__ float fdot2_sw(half2_t a, half2_t b, float c) {
    return fmaf((float)a.x, (float)b.x, fmaf((float)a.y, (float)b.y, c));
}
#define FDOT2(a, b, c) fdot2_sw((a), (b), (c))
#endif

// ---------------- CSR build (by dst) ----------------

__global__ void k_hist(const int* __restrict__ dst, int* __restrict__ deg) {
    int e = blockIdx.x * blockDim.x + threadIdx.x;
    if (e < N_EDGES) atomicAdd(&deg[dst[e]], 1);
}

__global__ void k_scan1(const int* __restrict__ deg, int* __restrict__ out1,
                        int* __restrict__ bsum) {
    __shared__ int s[256];
    int t = threadIdx.x;
    int base = blockIdx.x * 1024;
    int v[4]; int sum = 0;
#pragma unroll
    for (int j = 0; j < 4; j++) {
        int idx = base + t * 4 + j;
        int x = (idx < N_NODES) ? deg[idx] : 0;
        v[j] = x; sum += x;
    }
    s[t] = sum;
    __syncthreads();
    for (int d2 = 1; d2 < 256; d2 <<= 1) {
        int val = (t >= d2) ? s[t - d2] : 0;
        __syncthreads();
        s[t] += val;
        __syncthreads();
    }
    int run = (t > 0) ? s[t - 1] : 0;
#pragma unroll
    for (int j = 0; j < 4; j++) {
        int idx = base + t * 4 + j;
        run += v[j];
        if (idx < N_NODES) out1[idx] = run;
    }
    if (t == 255) bsum[blockIdx.x] = s[255];
}

__global__ void k_scan2(int* bsum, int nb) {
    if (threadIdx.x == 0 && blockIdx.x == 0) {
        int run = 0;
        for (int i = 0; i < nb; i++) { int v = bsum[i]; bsum[i] = run; run += v; }
    }
}

__global__ void k_scanadd(int* __restrict__ off, const int* __restrict__ bsum,
                          int* __restrict__ head) {
    int i = blockIdx.x * blockDim.x + threadIdx.x;
    if (i == 0) { off[0] = 0; head[0] = 0; }
    if (i < N_NODES) {
        int v = off[i + 1] + bsum[i / 1024];
        off[i + 1] = v;
        if (i + 1 < N_NODES) head[i + 1] = v;
    }
}

__global__ void k_scatter(const int* __restrict__ src, const int* __restrict__ dst,
                          int* __restrict__ head, int2* __restrict__ sorted) {
    int e = blockIdx.x * blockDim.x + threadIdx.x;
    if (e < N_EDGES) {
        int d = dst[e];
        int pos = atomicAdd(&head[d], 1);
        sorted[pos] = make_int2(src[e], e);
    }
}

// ---------------- dtype conversion / weight packing ----------------

__global__ void k_f32_to_f16(const float* __restrict__ in, _Float16* __restrict__ out,
                             int n) {
    int i = blockIdx.x * blockDim.x + threadIdx.x;
    int base = i * 8;
    if (base >= n) return;
    float4 a = *(const float4*)(in + base);
    float4 b = *(const float4*)(in + base + 4);
    half8_t h = {(_Float16)a.x, (_Float16)a.y, (_Float16)a.z, (_Float16)a.w,
                 (_Float16)b.x, (_Float16)b.y, (_Float16)b.z, (_Float16)b.w};
    *(half8_t*)(out + base) = h;
}

// Pack W1/W2 (DEPTH layers) into MFMA B-fragment order, f16.
// Per matrix (16384 elems): idx = ((kb*8+nb)*64 + lane)*8 + j holds
// W[kb*32 + (lane>>4)*8 + j][nb*16 + (lane&15)].
__global__ void k_pack_w(const float* __restrict__ W1, const float* __restrict__ W2,
                         _Float16* __restrict__ Wp) {
    int t = blockIdx.x * blockDim.x + threadIdx.x;
    if (t >= 6 * 16384) return;
    int j    = t & 7;
    int lane = (t >> 3) & 63;
    int nb   = (t >> 9) & 7;
    int kb   = (t >> 12) & 3;
    int mat  = t >> 14;             // 0..5 = (layer, which)
    int layer = mat >> 1, which = mat & 1;
    const float* Wsrc = (which ? W2 : W1) + (size_t)layer * D * D;
    int k = kb * 32 + (lane >> 4) * 8 + j;
    int n = nb * 16 + (lane & 15);
    Wp[t] = (_Float16)Wsrc[k * D + n];
}

// ---------------- per-layer: aggregation (one wave per node) ----------------
// h0[i] = (1+eps)*x[i] + sum_{e: dst==i} relu(x[src_e] + edge_attr[e]@We + be)
// x/h0 stored f16 (2 feats/lane as one uint); edge proj via v_dot2_f32_f16.

__global__ __launch_bounds__(256) void k_agg(
    const _Float16* __restrict__ xb, const _Float16* __restrict__ eah,
    const int2* __restrict__ sorted, const int* __restrict__ off,
    const float* __restrict__ We_l, const float* __restrict__ be_l,
    const float* __restrict__ eps_ptr, _Float16* __restrict__ h0) {
    int wave = (blockIdx.x * blockDim.x + threadIdx.x) >> 6;
    int lane = threadIdx.x & 63;
    if (wave >= N_NODES) return;
    int f0 = 2 * lane, f1 = 2 * lane + 1;

    half2_t wc0[8], wc1[8];
#pragma unroll
    for (int kk = 0; kk < 8; kk++) {
        wc0[kk] = half2_t{(_Float16)We_l[(2 * kk) * D + f0],
                          (_Float16)We_l[(2 * kk + 1) * D + f0]};
        wc1[kk] = half2_t{(_Float16)We_l[(2 * kk) * D + f1],
                          (_Float16)We_l[(2 * kk + 1) * D + f1]};
    }
    float be0 = be_l[f0], be1 = be_l[f1];

    const unsigned* xw = (const unsigned*)xb;   // 2 f16 per word, row = 64 words

    float acc0 = 0.f, acc1 = 0.f;
    int t0 = __builtin_amdgcn_readfirstlane(off[wave]);
    int t1 = __builtin_amdgcn_readfirstlane(off[wave + 1]);
    int t = t0;

    for (; t + 8 <= t1; t += 8) {
        int es[8], ee[8];
#pragma unroll
        for (int u = 0; u < 8; u++) {
            int2 se = sorted[t + u];
            es[u] = __builtin_amdgcn_readfirstlane(se.x);
            ee[u] = __builtin_amdgcn_readfirstlane(se.y);
        }
        unsigned xv[8];
#pragma unroll
        for (int u = 0; u < 8; u++) xv[u] = xw[(size_t)es[u] * 64 + lane];
        half2_t ev[8][8];
#pragma unroll
        for (int u = 0; u < 8; u++) {
            const half2_t* ep = (const half2_t*)(eah + (size_t)ee[u] * E_DIM);
#pragma unroll
            for (int kk = 0; kk < 8; kk++) ev[u][kk] = ep[kk];
        }
#pragma unroll
        for (int u = 0; u < 8; u++) {
            float p0 = be0, p1 = be1;
#pragma unroll
            for (int kk = 0; kk < 8; kk++) {
                p0 = FDOT2(ev[u][kk], wc0[kk], p0);
                p1 = FDOT2(ev[u][kk], wc1[kk], p1);
            }
            half2_t xh = __builtin_bit_cast(half2_t, xv[u]);
            acc0 += fmaxf((float)xh.x + p0, 0.f);
            acc1 += fmaxf((float)xh.y + p1, 0.f);
        }
    }
    for (; t < t1; ++t) {
        int2 se = sorted[t];
        int s = __builtin_amdgcn_readfirstlane(se.x);
        int e = __builtin_amdgcn_readfirstlane(se.y);
        unsigned xv = xw[(size_t)s * 64 + lane];
        const half2_t* ep = (const half2_t*)(eah + (size_t)e * E_DIM);
        float p0 = be0, p1 = be1;
#pragma unroll
        for (int kk = 0; kk < 8; kk++) {
            half2_t evk = ep[kk];
            p0 = FDOT2(evk, wc0[kk], p0);
            p1 = FDOT2(evk, wc1[kk], p1);
        }
        half2_t xh = __builtin_bit_cast(half2_t, xv);
        acc0 += fmaxf((float)xh.x + p0, 0.f);
        acc1 += fmaxf((float)xh.y + p1, 0.f);
    }

    float epsv = 1.0f + eps_ptr[0];
    half2_t xh = __builtin_bit_cast(half2_t, xw[(size_t)wave * 64 + lane]);
    float o0 = fmaf(epsv, (float)xh.x, acc0);
    float o1 = fmaf(epsv, (float)xh.y, acc1);
    half2_t oh = half2_t{(_Float16)o0, (_Float16)o1};
    ((unsigned*)h0)[(size_t)wave * 64 + lane] = __builtin_bit_cast(unsigned, oh);
}

// ---------------- per-layer: fused node MLP via MFMA f16 ----------------
// out = gelu_exact(h0 @ W1 + b1) @ W2 + b2
// Block = 256 thr (4 waves), 64 nodes. Wave w owns node stripe [w*16, w*16+16).
// A-frag: lane holds A[m=lane&15][k=(lane>>4)*8 + j] (8 contiguous f16).
// C/D: col=lane&15, row=(lane>>4)*4+reg  [verified layout].

template <bool LAST>
__global__ __launch_bounds__(256) void k_mlp(
    const _Float16* __restrict__ h0, const _Float16* __restrict__ W1p,
    const float* __restrict__ b1, const _Float16* __restrict__ W2p,
    const float* __restrict__ b2, float* __restrict__ outf,
    _Float16* __restrict__ outh) {
    __shared__ _Float16 sH[64 * 136];   // +8 pad -> ds_read_b128 2-way max
    __shared__ _Float16 sG[64 * 136];
    int n0 = blockIdx.x * 64;
    int t = threadIdx.x;

    // stage h tile: 64 rows x 128 f16 = 1024 x 16B chunks
    for (int c = t; c < 1024; c += 256) {
        int row = c >> 4, cc = c & 15;
        uint4 v = make_uint4(0, 0, 0, 0);
        if (n0 + row < N_NODES)
            v = *(const uint4*)(h0 + (size_t)(n0 + row) * D + cc * 8);
        *(uint4*)&sH[row * 136 + cc * 8] = v;
    }
    __syncthreads();

    int w = t >> 6, lane = t & 63, q = lane >> 4, r16 = lane & 15;
    int mrow = w * 16 + r16;

    // ---- phase 1: G = gelu(H @ W1 + b1) ----
    floatx4 acc[8];
#pragma unroll
    for (int nb = 0; nb < 8; nb++) acc[nb] = floatx4{0.f, 0.f, 0.f, 0.f};
#pragma unroll
    for (int kb = 0; kb < 4; kb++) {
        half8_t av = *(const half8_t*)&sH[mrow * 136 + kb * 32 + q * 8];
#pragma unroll
        for (int nb = 0; nb < 8; nb++) {
            half8_t bv = *(const half8_t*)(W1p + (size_t)((kb * 8 + nb) * 64 + lane) * 8);
            acc[nb] = __builtin_amdgcn_mfma_f32_16x16x32_f16(av, bv, acc[nb], 0, 0, 0);
        }
    }
#pragma unroll
    for (int nb = 0; nb < 8; nb++) {
        int col = nb * 16 + r16;
        float bb = b1[col];
#pragma unroll
        for (int r = 0; r < 4; r++) {
            float v = acc[nb][r] + bb;
            float g = 0.5f * v * (1.0f + erff(v * 0.70710678118654752f));
            sG[(w * 16 + q * 4 + r) * 136 + col] = (_Float16)g;
        }
    }
    // no __syncthreads: wave w writes exactly the sG rows it reads below

    // ---- phase 2: out = G @ W2 + b2 ----
#pragma unroll
    for (int nb = 0; nb < 8; nb++) acc[nb] = floatx4{0.f, 0.f, 0.f, 0.f};
#pragma unroll
    for (int kb = 0; kb < 4; kb++) {
        half8_t av = *(const half8_t*)&sG[mrow * 136 + kb * 32 + q * 8];
#pragma unroll
        for (int nb = 0; nb < 8; nb++) {
            half8_t bv = *(const half8_t*)(W2p + (size_t)((kb * 8 + nb) * 64 + lane) * 8);
            acc[nb] = __builtin_amdgcn_mfma_f32_16x16x32_f16(av, bv, acc[nb], 0, 0, 0);
        }
    }
#pragma unroll
    for (int nb = 0; nb < 8; nb++) {
        int col = nb * 16 + r16;
        float bb = b2[col];
#pragma unroll
        for (int r = 0; r < 4; r++) {
            int n = n0 + w * 16 + q * 4 + r;
            if (n < N_NODES) {
                float v = acc[nb][r] + bb;
                if (LAST) outf[(size_t)n * D + col] = v;
                else      outh[(size_t)n * D + col] = (_Float16)v;
            }
        }
    }
}

// ---------------- launch ----------------

static inline size_t align_up(size_t v, size_t a) { return (v + a - 1) & ~(a - 1); }

extern "C" void kernel_launch(void* const* d_in, const int* in_sizes, int n_in,
                              void* d_out, int out_size, void* d_ws, size_t ws_size,
                              hipStream_t stream) {
    const float* x         = (const float*)d_in[0];
    const float* edge_attr = (const float*)d_in[1];
    const float* W1        = (const float*)d_in[2];
    const float* b1        = (const float*)d_in[3];
    const float* W2        = (const float*)d_in[4];
    const float* b2        = (const float*)d_in[5];
    const float* We        = (const float*)d_in[6];
    const float* be        = (const float*)d_in[7];
    const float* eps       = (const float*)d_in[8];
    const int*   src       = (const int*)d_in[9];
    const int*   dst       = ((const int*)d_in[9]) + N_EDGES;

    char* w = (char*)d_ws;
    int*  off    = (int*)w;  w += align_up((N_NODES + 1) * sizeof(int), 16);
    int*  deg    = (int*)w;  w += align_up(N_NODES * sizeof(int), 16);
    int*  head   = (int*)w;  w += align_up(N_NODES * sizeof(int), 16);
    int*  bsum   = (int*)w;  w += 256;
    int2* sorted = (int2*)w; w += (size_t)N_EDGES * sizeof(int2);
    _Float16* xb0 = (_Float16*)w; w += (size_t)N_NODES * D * 2;
    _Float16* xb1 = (_Float16*)w; w += (size_t)N_NODES * D * 2;
    _Float16* h0b = (_Float16*)w; w += (size_t)N_NODES * D * 2;
    _Float16* eah = (_Float16*)w; w += (size_t)N_EDGES * E_DIM * 2;
    _Float16* Wp  = (_Float16*)w; w += (size_t)6 * 16384 * 2;

    // ---- CSR build ----
    hipMemsetAsync(deg, 0, N_NODES * sizeof(int), stream);
    k_hist<<<(N_EDGES + 255) / 256, 256, 0, stream>>>(dst, deg);
    int nb1 = (N_NODES + 1023) / 1024;
    k_scan1<<<nb1, 256, 0, stream>>>(deg, off + 1, bsum);
    k_scan2<<<1, 64, 0, stream>>>(bsum, nb1);
    k_scanadd<<<(N_NODES + 255) / 256, 256, 0, stream>>>(off, bsum, head);
    k_scatter<<<(N_EDGES + 255) / 256, 256, 0, stream>>>(src, dst, head, sorted);

    // ---- f16 conversions + weight packing ----
    k_f32_to_f16<<<(N_NODES * D / 8 + 255) / 256, 256, 0, stream>>>(x, xb0, N_NODES * D);
    k_f32_to_f16<<<(N_EDGES * E_DIM / 8 + 255) / 256, 256, 0, stream>>>(
        edge_attr, eah, N_EDGES * E_DIM);
    k_pack_w<<<(6 * 16384 + 255) / 256, 256, 0, stream>>>(W1, W2, Wp);

    // ---- 3 layers ----
    _Float16* xcur = xb0;
    _Float16* xnxt = xb1;
    for (int l = 0; l < DEPTH; l++) {
        k_agg<<<(N_NODES + 3) / 4, 256, 0, stream>>>(
            xcur, eah, sorted, off,
            We + (size_t)l * E_DIM * D, be + (size_t)l * D, eps + l, h0b);
        const _Float16* W1p = Wp + (size_t)(l * 2 + 0) * 16384;
        const _Float16* W2p = Wp + (size_t)(l * 2 + 1) * 16384;
        if (l == DEPTH - 1) {
            k_mlp<true><<<(N_NODES + 63) / 64, 256, 0, stream>>>(
                h0b, W1p, b1 + (size_t)l * D, W2p, b2 + (size_t)l * D,
                (float*)d_out, nullptr);
        } else {
            k_mlp<false><<<(N_NODES + 63) / 64, 256, 0, stream>>>(
                h0b, W1p, b1 + (size_t)l * D, W2p, b2 + (size_t)l * D,
                nullptr, xnxt);
        }
        _Float16* tmp = xcur; xcur = xnxt; xnxt = tmp;
    }
}

// Round 4
// 532.892 us; speedup vs baseline: 1.6811x; 1.0705x over previous
//
#include <hip/hip_runtime.h>
#include <math.h>

#define N_NODES 50000
#define N_EDGES 800000
#define D 128
#define E_DIM 16
#define DEPTH 3

typedef _Float16 half2_t __attribute__((ext_vector_type(2)));
typedef _Float16 half4_t __attribute__((ext_vector_type(4)));
typedef _Float16 half8_t __attribute__((ext_vector_type(8)));
typedef float floatx4 __attribute__((ext_vector_type(4)));

#if defined(__has_builtin)
#if __has_builtin(__builtin_amdgcn_fdot2)
#define FDOT2(a, b, c) __builtin_amdgcn_fdot2((a), (b), (c), false)
#endif
#endif
#ifndef FDOT2
static __device__ __forceinline__ float fdot2_sw(half2_t a, half2_t b, float c) {
    return fmaf((float)a.x, (float)b.x, fmaf((float)a.y, (float)b.y, c));
}
#define FDOT2(a, b, c) fdot2_sw((a), (b), (c))
#endif

// ---------------- CSR build (by dst) ----------------

__global__ void k_hist(const int* __restrict__ dst, int* __restrict__ deg) {
    int e = blockIdx.x * blockDim.x + threadIdx.x;
    if (e < N_EDGES) atomicAdd(&deg[dst[e]], 1);
}

__global__ void k_scan1(const int* __restrict__ deg, int* __restrict__ out1,
                        int* __restrict__ bsum) {
    __shared__ int s[256];
    int t = threadIdx.x;
    int base = blockIdx.x * 1024;
    int v[4]; int sum = 0;
#pragma unroll
    for (int j = 0; j < 4; j++) {
        int idx = base + t * 4 + j;
        int x = (idx < N_NODES) ? deg[idx] : 0;
        v[j] = x; sum += x;
    }
    s[t] = sum;
    __syncthreads();
    for (int d2 = 1; d2 < 256; d2 <<= 1) {
        int val = (t >= d2) ? s[t - d2] : 0;
        __syncthreads();
        s[t] += val;
        __syncthreads();
    }
    int run = (t > 0) ? s[t - 1] : 0;
#pragma unroll
    for (int j = 0; j < 4; j++) {
        int idx = base + t * 4 + j;
        run += v[j];
        if (idx < N_NODES) out1[idx] = run;
    }
    if (t == 255) bsum[blockIdx.x] = s[255];
}

// adds block-sum prefix (computed inline: <=48 adds over L1-broadcast values)
__global__ void k_scanadd(int* __restrict__ off, const int* __restrict__ bsum1,
                          int* __restrict__ head) {
    int i = blockIdx.x * blockDim.x + threadIdx.x;
    if (i == 0) { off[0] = 0; head[0] = 0; }
    if (i < N_NODES) {
        int nb = i >> 10;
        int add = 0;
        for (int j = 0; j < nb; j++) add += bsum1[j];
        int v = off[i + 1] + add;
        off[i + 1] = v;
        if (i + 1 < N_NODES) head[i + 1] = v;
    }
}

__global__ void k_scatter(const int* __restrict__ src, const int* __restrict__ dst,
                          int* __restrict__ head, int2* __restrict__ sorted) {
    int e = blockIdx.x * blockDim.x + threadIdx.x;
    if (e < N_EDGES) {
        int d = dst[e];
        int pos = atomicAdd(&head[d], 1);
        sorted[pos] = make_int2(src[e], e);
    }
}

// ---------------- prep: f16 converts + MFMA weight packing (one kernel) ------

#define NB_X   3125    // N_NODES*D/8/256
#define NB_EA  6250    // N_EDGES*E_DIM/8/256
#define NB_W   384     // 6*16384/256

__global__ void k_prep(const float* __restrict__ x, const float* __restrict__ ea,
                       const float* __restrict__ W1, const float* __restrict__ W2,
                       _Float16* __restrict__ xh, _Float16* __restrict__ eah,
                       _Float16* __restrict__ Wp) {
    int b = blockIdx.x;
    if (b < NB_X + NB_EA) {
        const float* in = (b < NB_X) ? x : ea;
        _Float16* out = (b < NB_X) ? xh : eah;
        int i = (b < NB_X) ? (b * 256 + threadIdx.x) : ((b - NB_X) * 256 + threadIdx.x);
        int base = i * 8;
        float4 a = *(const float4*)(in + base);
        float4 c = *(const float4*)(in + base + 4);
        half8_t h = {(_Float16)a.x, (_Float16)a.y, (_Float16)a.z, (_Float16)a.w,
                     (_Float16)c.x, (_Float16)c.y, (_Float16)c.z, (_Float16)c.w};
        *(half8_t*)(out + base) = h;
    } else {
        int t = (b - NB_X - NB_EA) * 256 + threadIdx.x;
        int j    = t & 7;
        int lane = (t >> 3) & 63;
        int nb   = (t >> 9) & 7;
        int kb   = (t >> 12) & 3;
        int mat  = t >> 14;
        int layer = mat >> 1, which = mat & 1;
        const float* Wsrc = (which ? W2 : W1) + (size_t)layer * D * D;
        int k = kb * 32 + (lane >> 4) * 8 + j;
        int n = nb * 16 + (lane & 15);
        Wp[t] = (_Float16)Wsrc[k * D + n];
    }
}

// ---------------- per-layer: aggregation ----------------
// One wave per dst node; 2 groups x 32 lanes; lane handles 4 feats (4c..4c+3);
// group g processes edges t0+g, t0+g+2, ... (2 edges in flight per group via
// unroll-2 => 4 gathers in flight per wave). Cross-group butterfly at end.

__global__ __launch_bounds__(256) void k_agg(
    const _Float16* __restrict__ xb, const _Float16* __restrict__ eah,
    const int2* __restrict__ sorted, const int* __restrict__ off,
    const float* __restrict__ We_l, const float* __restrict__ be_l,
    const float* __restrict__ eps_ptr, _Float16* __restrict__ h0) {
    int n = blockIdx.x * 4 + (threadIdx.x >> 6);
    if (n >= N_NODES) return;
    int lane = threadIdx.x & 63;
    int g = lane >> 5;        // group 0/1
    int c = lane & 31;        // feature slice: feats 4c..4c+3

    // We pairs (k-pairs x 4 feats) in registers; loaded as float4 rows
    half2_t w2[8][4];
    float bev[4];
    {
        float4 bb = *(const float4*)(be_l + 4 * c);
        bev[0] = bb.x; bev[1] = bb.y; bev[2] = bb.z; bev[3] = bb.w;
#pragma unroll
        for (int kp = 0; kp < 8; kp++) {
            float4 r0 = *(const float4*)(We_l + (2 * kp) * D + 4 * c);
            float4 r1 = *(const float4*)(We_l + (2 * kp + 1) * D + 4 * c);
            w2[kp][0] = half2_t{(_Float16)r0.x, (_Float16)r1.x};
            w2[kp][1] = half2_t{(_Float16)r0.y, (_Float16)r1.y};
            w2[kp][2] = half2_t{(_Float16)r0.z, (_Float16)r1.z};
            w2[kp][3] = half2_t{(_Float16)r0.w, (_Float16)r1.w};
        }
    }

    float acc[4] = {0.f, 0.f, 0.f, 0.f};
    int t0 = __builtin_amdgcn_readfirstlane(off[n]);
    int t1 = __builtin_amdgcn_readfirstlane(off[n + 1]);

    auto process = [&](int te) {
        int2 se = sorted[te];
        const _Float16* ep = eah + (size_t)se.y * E_DIM;
        half8_t elo = *(const half8_t*)ep;
        half8_t ehi = *(const half8_t*)(ep + 8);
        half4_t xv = *(const half4_t*)(xb + (size_t)se.x * D + 4 * c);
        float p0 = bev[0], p1 = bev[1], p2 = bev[2], p3 = bev[3];
#pragma unroll
        for (int kp = 0; kp < 4; kp++) {
            half2_t e2 = half2_t{elo[2 * kp], elo[2 * kp + 1]};
            p0 = FDOT2(e2, w2[kp][0], p0);
            p1 = FDOT2(e2, w2[kp][1], p1);
            p2 = FDOT2(e2, w2[kp][2], p2);
            p3 = FDOT2(e2, w2[kp][3], p3);
        }
#pragma unroll
        for (int kp = 0; kp < 4; kp++) {
            half2_t e2 = half2_t{ehi[2 * kp], ehi[2 * kp + 1]};
            p0 = FDOT2(e2, w2[kp + 4][0], p0);
            p1 = FDOT2(e2, w2[kp + 4][1], p1);
            p2 = FDOT2(e2, w2[kp + 4][2], p2);
            p3 = FDOT2(e2, w2[kp + 4][3], p3);
        }
        acc[0] += fmaxf((float)xv[0] + p0, 0.f);
        acc[1] += fmaxf((float)xv[1] + p1, 0.f);
        acc[2] += fmaxf((float)xv[2] + p2, 0.f);
        acc[3] += fmaxf((float)xv[3] + p3, 0.f);
    };

    int t = t0;
    for (; t + 4 <= t1; t += 4) {      // both groups, 2 slots each
        process(t + g);
        process(t + g + 2);
    }
    for (; t < t1; t += 2) {           // remainder (<=3 edges)
        int te = t + g;
        if (te < t1) process(te);
    }

    // cross-group reduction: lane l += lane l^32
#pragma unroll
    for (int f = 0; f < 4; f++) acc[f] += __shfl_xor(acc[f], 32, 64);

    if (g == 0) {
        float epsv = 1.0f + eps_ptr[0];
        half4_t xv = *(const half4_t*)(xb + (size_t)n * D + 4 * c);
        half4_t oh;
#pragma unroll
        for (int f = 0; f < 4; f++)
            oh[f] = (_Float16)(fmaf(epsv, (float)xv[f], acc[f]));
        *(half4_t*)(h0 + (size_t)n * D + 4 * c) = oh;
    }
}

// ---------------- per-layer: fused node MLP via MFMA f16 ----------------

template <bool LAST>
__global__ __launch_bounds__(256) void k_mlp(
    const _Float16* __restrict__ h0, const _Float16* __restrict__ W1p,
    const float* __restrict__ b1, const _Float16* __restrict__ W2p,
    const float* __restrict__ b2, float* __restrict__ outf,
    _Float16* __restrict__ outh) {
    __shared__ _Float16 sH[64 * 136];
    __shared__ _Float16 sG[64 * 136];
    int n0 = blockIdx.x * 64;
    int t = threadIdx.x;

    for (int cc = t; cc < 1024; cc += 256) {
        int row = cc >> 4, c4 = cc & 15;
        uint4 v = make_uint4(0, 0, 0, 0);
        if (n0 + row < N_NODES)
            v = *(const uint4*)(h0 + (size_t)(n0 + row) * D + c4 * 8);
        *(uint4*)&sH[row * 136 + c4 * 8] = v;
    }
    __syncthreads();

    int w = t >> 6, lane = t & 63, q = lane >> 4, r16 = lane & 15;
    int mrow = w * 16 + r16;

    floatx4 acc[8];
#pragma unroll
    for (int nb = 0; nb < 8; nb++) acc[nb] = floatx4{0.f, 0.f, 0.f, 0.f};
#pragma unroll
    for (int kb = 0; kb < 4; kb++) {
        half8_t av = *(const half8_t*)&sH[mrow * 136 + kb * 32 + q * 8];
#pragma unroll
        for (int nb = 0; nb < 8; nb++) {
            half8_t bv = *(const half8_t*)(W1p + (size_t)((kb * 8 + nb) * 64 + lane) * 8);
            acc[nb] = __builtin_amdgcn_mfma_f32_16x16x32_f16(av, bv, acc[nb], 0, 0, 0);
        }
    }
#pragma unroll
    for (int nb = 0; nb < 8; nb++) {
        int col = nb * 16 + r16;
        float bb = b1[col];
#pragma unroll
        for (int r = 0; r < 4; r++) {
            float v = acc[nb][r] + bb;
            float gl = 0.5f * v * (1.0f + erff(v * 0.70710678118654752f));
            sG[(w * 16 + q * 4 + r) * 136 + col] = (_Float16)gl;
        }
    }
    // wave w writes exactly the sG rows it reads below — no barrier needed

#pragma unroll
    for (int nb = 0; nb < 8; nb++) acc[nb] = floatx4{0.f, 0.f, 0.f, 0.f};
#pragma unroll
    for (int kb = 0; kb < 4; kb++) {
        half8_t av = *(const half8_t*)&sG[mrow * 136 + kb * 32 + q * 8];
#pragma unroll
        for (int nb = 0; nb < 8; nb++) {
            half8_t bv = *(const half8_t*)(W2p + (size_t)((kb * 8 + nb) * 64 + lane) * 8);
            acc[nb] = __builtin_amdgcn_mfma_f32_16x16x32_f16(av, bv, acc[nb], 0, 0, 0);
        }
    }
#pragma unroll
    for (int nb = 0; nb < 8; nb++) {
        int col = nb * 16 + r16;
        float bb = b2[col];
#pragma unroll
        for (int r = 0; r < 4; r++) {
            int n = n0 + w * 16 + q * 4 + r;
            if (n < N_NODES) {
                float v = acc[nb][r] + bb;
                if (LAST) outf[(size_t)n * D + col] = v;
                else      outh[(size_t)n * D + col] = (_Float16)v;
            }
        }
    }
}

// ---------------- launch ----------------

static inline size_t align_up(size_t v, size_t a) { return (v + a - 1) & ~(a - 1); }

extern "C" void kernel_launch(void* const* d_in, const int* in_sizes, int n_in,
                              void* d_out, int out_size, void* d_ws, size_t ws_size,
                              hipStream_t stream) {
    const float* x         = (const float*)d_in[0];
    const float* edge_attr = (const float*)d_in[1];
    const float* W1        = (const float*)d_in[2];
    const float* b1        = (const float*)d_in[3];
    const float* W2        = (const float*)d_in[4];
    const float* b2        = (const float*)d_in[5];
    const float* We        = (const float*)d_in[6];
    const float* be        = (const float*)d_in[7];
    const float* eps       = (const float*)d_in[8];
    const int*   src       = (const int*)d_in[9];
    const int*   dst       = ((const int*)d_in[9]) + N_EDGES;

    char* w = (char*)d_ws;
    int*  off    = (int*)w;  w += align_up((N_NODES + 1) * sizeof(int), 16);
    int*  deg    = (int*)w;  w += align_up(N_NODES * sizeof(int), 16);
    int*  head   = (int*)w;  w += align_up(N_NODES * sizeof(int), 16);
    int*  bsum   = (int*)w;  w += 256;
    int2* sorted = (int2*)w; w += (size_t)N_EDGES * sizeof(int2);
    _Float16* xb0 = (_Float16*)w; w += (size_t)N_NODES * D * 2;
    _Float16* xb1 = (_Float16*)w; w += (size_t)N_NODES * D * 2;
    _Float16* h0b = (_Float16*)w; w += (size_t)N_NODES * D * 2;
    _Float16* eah = (_Float16*)w; w += (size_t)N_EDGES * E_DIM * 2;
    _Float16* Wp  = (_Float16*)w; w += (size_t)6 * 16384 * 2;

    // ---- CSR build ----
    hipMemsetAsync(deg, 0, N_NODES * sizeof(int), stream);
    k_hist<<<(N_EDGES + 255) / 256, 256, 0, stream>>>(dst, deg);
    int nb1 = (N_NODES + 1023) / 1024;
    k_scan1<<<nb1, 256, 0, stream>>>(deg, off + 1, bsum);
    k_scanadd<<<(N_NODES + 255) / 256, 256, 0, stream>>>(off, bsum, head);
    k_scatter<<<(N_EDGES + 255) / 256, 256, 0, stream>>>(src, dst, head, sorted);

    // ---- prep: converts + weight packing ----
    k_prep<<<NB_X + NB_EA + NB_W, 256, 0, stream>>>(x, edge_attr, W1, W2, xb0, eah, Wp);

    // ---- 3 layers ----
    _Float16* xcur = xb0;
    _Float16* xnxt = xb1;
    for (int l = 0; l < DEPTH; l++) {
        k_agg<<<(N_NODES + 3) / 4, 256, 0, stream>>>(
            xcur, eah, sorted, off,
            We + (size_t)l * E_DIM * D, be + (size_t)l * D, eps + l, h0b);
        const _Float16* W1p = Wp + (size_t)(l * 2 + 0) * 16384;
        const _Float16* W2p = Wp + (size_t)(l * 2 + 1) * 16384;
        if (l == DEPTH - 1) {
            k_mlp<true><<<(N_NODES + 63) / 64, 256, 0, stream>>>(
                h0b, W1p, b1 + (size_t)l * D, W2p, b2 + (size_t)l * D,
                (float*)d_out, nullptr);
        } else {
            k_mlp<false><<<(N_NODES + 63) / 64, 256, 0, stream>>>(
                h0b, W1p, b1 + (size_t)l * D, W2p, b2 + (size_t)l * D,
                nullptr, xnxt);
        }
        _Float16* tmp = xcur; xcur = xnxt; xnxt = tmp;
    }
}